// Round 9
// baseline (4501.320 us; speedup 1.0000x reference)
//
#include <hip/hip_runtime.h>
#include <hip/hip_bf16.h>

// 2-layer LSTM, B=64 T=2048 D=H=256, fp32 I/O.
// v9: scan 4-way k-split, pure-VGPR weight residency.
//   Round-8 evidence: scan = 9 x 425us = 97% of total; VALU-busy 2600 cyc/step
//   vs 1024-cyc dot2 floor. VGPR_Count=128 under launch_bounds(512,2) shows
//   the compiler split 128V+128A and wr[] uses pay v_accvgpr_read per step
//   (~740+ cyc/SIMD overhead). Fix: 1024 thr/WG (4 waves/SIMD, 128-reg cap),
//   thread owns 32 k2-blocks: 23 in VGPR (92 regs, no AGPR) + 9 in LDS.
//   LDS = 147456 (wl) + 12288 (red) + 512 (hf) = 160256 <= 160 KiB.
//   Pipeline structure (dual-job slots, chunked gemms) unchanged.

typedef unsigned short u16;
typedef unsigned int   u32;

typedef __attribute__((ext_vector_type(8))) _Float16       half8;
typedef __attribute__((ext_vector_type(2))) _Float16       half2_t;
typedef __attribute__((ext_vector_type(8))) unsigned short ushort8;
typedef __attribute__((ext_vector_type(4))) float          f32x4;

#define B_  64
#define T_  2048
#define D_  256
#define H_  256
#define G_  1024   // 4*H

#define NRG 23     // scan: k2-blocks per thread in VGPRs
#define NLD 9      // scan: k2-blocks per thread in LDS (NRG+NLD = 32)
static_assert(NRG + NLD == 32, "quarter k-split coverage");

// ---- helpers ----
__device__ __forceinline__ u16 f2h(float f) {           // RNE fp32->fp16
    union { _Float16 h; u16 b; } v; v.h = (_Float16)f; return v.b;
}
__device__ __forceinline__ float dot2(u32 w, u32 hv, float acc) {
#if __has_builtin(__builtin_amdgcn_fdot2)
    union { u32 u; half2_t h; } a, b;
    a.u = w; b.u = hv;
    return __builtin_amdgcn_fdot2(a.h, b.h, acc, false);
#else
    union { u32 u; _Float16 h[2]; } a, b;
    a.u = w; b.u = hv;
    acc += (float)a.h[0] * (float)b.h[0];
    acc += (float)a.h[1] * (float)b.h[1];
    return acc;
#endif
}
__device__ __forceinline__ float sigm(float x) {
    return 1.0f / (1.0f + __expf(-x));
}
__device__ __forceinline__ float tanh_(float x) {
    float e = __expf(-2.0f * fabsf(x));
    float r = (1.0f - e) / (1.0f + e);
    return x < 0.0f ? -r : r;
}

// ---- pack W_hh [1024][256] fp32 -> Wp[k2][j] = uint4{i,f,g,o} f16-pairs --
__global__ __launch_bounds__(256) void pack_whh(
    const float* __restrict__ W0, const float* __restrict__ W1,
    uint4* __restrict__ P0, uint4* __restrict__ P1)
{
    const int k2 = blockIdx.x;          // 0..127
    const int j  = threadIdx.x;         // 0..255
    const float* W = blockIdx.y ? W1 : W0;
    uint4*       P = blockIdx.y ? P1 : P0;
    uint4 v;
    u32* vp = &v.x;
#pragma unroll
    for (int g = 0; g < 4; ++g) {
        float2 w = *(const float2*)(W + (size_t)(g * 256 + j) * 256 + 2 * k2);
        vp[g] = (u32)f2h(w.x) | ((u32)f2h(w.y) << 16);
    }
    P[(size_t)k2 * 256 + j] = v;
}

// ---- pack W_ih [1024][256] fp32 -> f16 row-major (both layers) ----
__global__ __launch_bounds__(256) void pack_wih(
    const float* __restrict__ W0, const float* __restrict__ W1,
    u16* __restrict__ O0, u16* __restrict__ O1)
{
    const float* W = blockIdx.y ? W1 : W0;
    u16*         O = blockIdx.y ? O1 : O0;
    size_t i = (size_t)blockIdx.x * 256 + threadIdx.x;   // over 65536 float4
    float4 v = ((const float4*)W)[i];
    u32 lo = (u32)f2h(v.x) | ((u32)f2h(v.y) << 16);
    u32 hi = (u32)f2h(v.z) | ((u32)f2h(v.w) << 16);
    uint2 u; u.x = lo; u.y = hi;
    ((uint2*)O)[i] = u;
}

// ---- xg GEMM: out[m][n] = sum_k A[grow(m)][k] * Bh[n][k], f16 MFMA ----
// One WG per 64-row M-tile; A staged once in LDS f16; full N=1024 loop.
// grow = (m>>tclog2)*Tstride + t0 + (m&tcmask).
template<int AHALF>
__global__ __launch_bounds__(256) void gemm_xg(
    const void* __restrict__ Av, const u16* __restrict__ Bh,
    u16* __restrict__ out, int tclog2, int Tstride, int t0)
{
    __shared__ __align__(16) u16 As[64][264];   // 33792 B
    const int tid    = threadIdx.x;
    const int m0     = blockIdx.x * 64;
    const int tcmask = (1 << tclog2) - 1;

    if (AHALF) {
        const u16* Ah = (const u16*)Av;
#pragma unroll
        for (int it = 0; it < 8; ++it) {
            int idx = it * 256 + tid;            // 2048 = 64 rows x 32 u16x8
            int row = idx >> 5;
            int c8  = idx & 31;
            int m   = m0 + row;
            size_t grow = (size_t)(m >> tclog2) * Tstride + t0 + (m & tcmask);
            ushort8 v = *(const ushort8*)(Ah + grow * D_ + c8 * 8);
            *(ushort8*)(&As[row][c8 * 8]) = v;
        }
    } else {
        const float* Af = (const float*)Av;
#pragma unroll
        for (int it = 0; it < 16; ++it) {
            int idx = it * 256 + tid;            // 4096 = 64 rows x 64 f32x4
            int row = idx >> 6;
            int c4  = idx & 63;
            int m   = m0 + row;
            size_t grow = (size_t)(m >> tclog2) * Tstride + t0 + (m & tcmask);
            float4 v = *(const float4*)(Af + grow * D_ + c4 * 4);
            uint2 u;
            u.x = (u32)f2h(v.x) | ((u32)f2h(v.y) << 16);
            u.y = (u32)f2h(v.z) | ((u32)f2h(v.w) << 16);
            *(uint2*)(&As[row][c4 * 4]) = u;
        }
    }
    __syncthreads();

    const int l   = tid & 63;
    const int w   = tid >> 6;
    const int rl  = l & 15;
    const int kg  = l >> 4;
    const int rr0 = kg * 4;

    for (int nb = 0; nb < 8; ++nb) {
        const int n0 = nb * 128 + w * 32;
        f32x4 zz = {0.f, 0.f, 0.f, 0.f};
        f32x4 acc[4][2];
#pragma unroll
        for (int mi = 0; mi < 4; ++mi)
#pragma unroll
            for (int ni = 0; ni < 2; ++ni) acc[mi][ni] = zz;

#pragma unroll
        for (int ks = 0; ks < 8; ++ks) {
            const int k = ks * 32 + kg * 8;
            half8 a[4], bb[2];
#pragma unroll
            for (int mi = 0; mi < 4; ++mi)
                a[mi] = *(const half8*)(&As[mi * 16 + rl][k]);
#pragma unroll
            for (int ni = 0; ni < 2; ++ni)
                bb[ni] = *(const half8*)(Bh + (size_t)(n0 + ni * 16 + rl) * D_ + k);
#pragma unroll
            for (int mi = 0; mi < 4; ++mi)
#pragma unroll
                for (int ni = 0; ni < 2; ++ni)
                    acc[mi][ni] = __builtin_amdgcn_mfma_f32_16x16x32_f16(
                        a[mi], bb[ni], acc[mi][ni], 0, 0, 0);
        }

        // C/D layout: col = lane&15, row = (lane>>4)*4 + reg
#pragma unroll
        for (int mi = 0; mi < 4; ++mi)
#pragma unroll
            for (int ni = 0; ni < 2; ++ni) {
                f32x4 d = acc[mi][ni];
                size_t mrow = (size_t)(m0 + mi * 16 + rr0);
                int col = n0 + ni * 16 + rl;
#pragma unroll
                for (int r = 0; r < 4; ++r)
                    out[(mrow + r) * G_ + col] = f2h(d[r]);
            }
    }
}

// ---- dual-job sequential scan: 128 WGs = 2 jobs x 64 batch elements ----
// WGs [0,64): job A; WGs [64,128): job B. 1024 threads: thread (j, kq) owns
// hidden unit j, k2-quarter kq (32 blocks: 23 VGPR + 9 LDS). h broadcast as
// f16 pairs in LDS; quarters 1-3 write float4 partials; kq0 does epilogue.
struct ScanJob {
    const _Float16* xg;      // [64][Tc][1024] f16
    const uint4*    Wp;      // [128][256]
    const float*    bias;    // [1024]
    float*          state;   // h[64][256], c[64][256]
    void*           h_out;   // f16 (houth=1) or fp32
    float*          hc_last; // may be null
    int Tc;                  // 0 = inactive
    int toff;                // h_out time offset
    int TS;                  // h_out time stride
    int houth;               // 1 = f16 h_out
    int first;               // 1 = zero-init state
};

__global__ __launch_bounds__(1024, 4) void lstm_scan2(ScanJob JA, ScanJob JB)
{
    const ScanJob J = (blockIdx.x >= 64) ? JB : JA;
    if (J.Tc == 0) return;
    const int b   = blockIdx.x & 63;
    const int tid = threadIdx.x;
    const int j   = tid & 255;
    const int kq  = tid >> 8;        // quarter 0..3

    __shared__ __align__(16) uint4  wl[NLD][1024];  // 147456 B
    __shared__ __align__(16) u32    hf_p[128];      //    512 B (f16 pairs)
    __shared__ __align__(16) float4 red[3 * 256];   //  12288 B

    // ---- one-time weight residency (per thread: k2 = kq*32 + p) ----
    const uint4* wpb = J.Wp + (size_t)(kq * 32) * 256 + j;
    uint4 wr[NRG];
#pragma unroll
    for (int p = 0; p < NRG; ++p)
        wr[p] = wpb[(size_t)p * 256];
#pragma unroll
    for (int p = 0; p < NLD; ++p)
        wl[p][tid] = wpb[(size_t)(NRG + p) * 256];

    const int Tc = J.Tc;
    const int houth = J.houth;
    float h = 0.f, c = 0.f;
    float bi = 0.f, bf_ = 0.f, bg = 0.f, bo = 0.f;
    const _Float16* xg = J.xg;
    size_t xo = (size_t)b * Tc * G_ + j;
    float nx0 = 0.f, nx1 = 0.f, nx2 = 0.f, nx3 = 0.f;
    _Float16* hfh = (_Float16*)hf_p;

    if (kq == 0) {
        if (!J.first) {
            h = J.state[b * H_ + j];
            c = J.state[B_ * H_ + b * H_ + j];
        }
        bi  = J.bias[j];
        bf_ = J.bias[256 + j];
        bg  = J.bias[512 + j];
        bo  = J.bias[768 + j];
        hfh[j] = (_Float16)h;
        nx0 = (float)xg[xo];       nx1 = (float)xg[xo + 256];
        nx2 = (float)xg[xo + 512]; nx3 = (float)xg[xo + 768];
    }
    const uint4* hv4p = ((const uint4*)hf_p) + kq * 8;   // 8 uint4 = 32 k2
    float* hof = (float*)J.h_out;
    u16*   hoh = (u16*)J.h_out;
    size_t ho = ((size_t)b * J.TS + J.toff) * H_ + j;
    __syncthreads();

    for (int t = 0; t < Tc; ++t) {
        float a0, a1, a2, a3;
        if (kq == 0) {
            a0 = nx0 + bi; a1 = nx1 + bf_; a2 = nx2 + bg; a3 = nx3 + bo;
            if (t + 1 < Tc) xo += G_;            // clamped prefetch
            nx0 = (float)xg[xo];       nx1 = (float)xg[xo + 256];
            nx2 = (float)xg[xo + 512]; nx3 = (float)xg[xo + 768];
        } else {
            a0 = a1 = a2 = a3 = 0.f;
        }

        // dot over this thread's 32 k2-blocks (4 per hv uint4)
#pragma unroll
        for (int i = 0; i < 8; ++i) {
            uint4 hv4 = hv4p[i];                 // broadcast read
            const u32* hq = &hv4.x;
#pragma unroll
            for (int q = 0; q < 4; ++q) {
                const int p = 4 * i + q;         // compile-time
                uint4 wv;
                if (p < NRG) wv = wr[p];
                else         wv = wl[p - NRG][tid];
                u32 hv = hq[q];
                a0 = dot2(wv.x, hv, a0);
                a1 = dot2(wv.y, hv, a1);
                a2 = dot2(wv.z, hv, a2);
                a3 = dot2(wv.w, hv, a3);
            }
        }

        if (kq > 0) {
            float4 r4; r4.x = a0; r4.y = a1; r4.z = a2; r4.w = a3;
            red[(kq - 1) * 256 + j] = r4;
        }
        __syncthreads();   // partials visible; all hv reads of step done
        if (kq == 0) {
            float4 p0 = red[j];
            float4 p1 = red[256 + j];
            float4 p2 = red[512 + j];
            a0 += p0.x + p1.x + p2.x;
            a1 += p0.y + p1.y + p2.y;
            a2 += p0.z + p1.z + p2.z;
            a3 += p0.w + p1.w + p2.w;
            float i_ = sigm(a0);
            float f_ = sigm(a1);
            float g_ = tanh_(a2);
            float o_ = sigm(a3);
            c = f_ * c + i_ * g_;
            float hn = o_ * tanh_(c);
            h = hn;
            hfh[j] = (_Float16)hn;
            if (houth) hoh[ho] = f2h(hn);
            else       __builtin_nontemporal_store(hn, hof + ho);
            ho += H_;
        }
        __syncthreads();   // new h visible
    }

    if (kq == 0) {
        J.state[b * H_ + j] = h;
        J.state[B_ * H_ + b * H_ + j] = c;
        if (J.hc_last) {
            J.hc_last[b * H_ + j] = h;
            J.hc_last[B_ * H_ + b * H_ + j] = c;
        }
    }
}

extern "C" void kernel_launch(void* const* d_in, const int* in_sizes, int n_in,
                              void* d_out, int out_size, void* d_ws, size_t ws_size,
                              hipStream_t stream)
{
    (void)in_sizes; (void)n_in; (void)out_size;

    const float* x    = (const float*)d_in[0];
    const float* Wih0 = (const float*)d_in[1];
    const float* Whh0 = (const float*)d_in[2];
    const float* b0   = (const float*)d_in[3];
    const float* Wih1 = (const float*)d_in[4];
    const float* Whh1 = (const float*)d_in[5];
    const float* b1   = (const float*)d_in[6];

    float* out   = (float*)d_out;
    float* hlast = out + (size_t)B_ * T_ * H_;

    // ws layout
    char* ws = (char*)d_ws;
    const size_t WPB  = (size_t)128 * 256 * 16;     // 524288 per packed W_hh
    const size_t WIHB = (size_t)1024 * 256 * 2;     // 524288 per f16 W_ih
    const size_t STB  = (size_t)2 * B_ * H_ * 4;    // 131072 per-layer state
    uint4* Wp0    = (uint4*)(ws);
    uint4* Wp1    = (uint4*)(ws + WPB);
    u16*   Wih0h  = (u16*)(ws + 2 * WPB);
    u16*   Wih1h  = (u16*)(ws + 2 * WPB + WIHB);
    float* state0 = (float*)(ws + 2 * WPB + 2 * WIHB);
    float* state1 = (float*)(ws + 2 * WPB + 2 * WIHB + STB);
    const size_t BASE = 2 * WPB + 2 * WIHB + 2 * STB;   // 2359296

    // Tc: largest power-of-2 <= 256 whose buffers fit ws.
    // per-Tc bytes: h1c 64*256*2 + xgA/xgB 2*64*1024*2 = 294912
    int Tc = 16;
    for (int tc = 256; tc >= 16; tc >>= 1)
        if (BASE + (size_t)tc * 294912 <= ws_size) { Tc = tc; break; }
    const int nch    = T_ / Tc;
    const int tclog2 = 31 - __builtin_clz((unsigned)Tc);
    const size_t H1CB = (size_t)B_ * Tc * H_ * 2;
    const size_t XGB  = (size_t)B_ * Tc * G_ * 2;
    u16*      h1c = (u16*)(ws + BASE);
    _Float16* xgA = (_Float16*)(ws + BASE + H1CB);
    _Float16* xgB = (_Float16*)(ws + BASE + H1CB + XGB);

    pack_whh<<<dim3(128, 2), 256, 0, stream>>>(Whh0, Whh1, Wp0, Wp1);
    pack_wih<<<dim3(256, 2), 256, 0, stream>>>(Wih0, Wih1, Wih0h, Wih1h);

    const int gemmWG = (B_ * Tc) / 64;

    // prologue: xg for layer-0 chunk 0
    gemm_xg<0><<<gemmWG, 256, 0, stream>>>(x, Wih0h, (u16*)xgA, tclog2, T_, 0);

    for (int s = 0; s <= nch; ++s) {
        ScanJob JA = {}; JA.Tc = 0;
        ScanJob JB = {}; JB.Tc = 0;
        if (s < nch) {                      // layer 0, chunk s
            JA.xg = xgA;  JA.Wp = Wp0;  JA.bias = b0;  JA.state = state0;
            JA.h_out = h1c;  JA.hc_last = nullptr;
            JA.Tc = Tc;  JA.toff = 0;  JA.TS = Tc;  JA.houth = 1;
            JA.first = (s == 0);
        }
        if (s >= 1) {                       // layer 1, chunk s-1
            int c = s - 1;
            JB.xg = xgB;  JB.Wp = Wp1;  JB.bias = b1;  JB.state = state1;
            JB.h_out = out;  JB.hc_last = (c == nch - 1) ? hlast : nullptr;
            JB.Tc = Tc;  JB.toff = c * Tc;  JB.TS = T_;  JB.houth = 0;
            JB.first = (c == 0);
        }
        lstm_scan2<<<128, 1024, 0, stream>>>(JA, JB);

        if (s + 1 < nch)                    // xg for layer-0 chunk s+1
            gemm_xg<0><<<gemmWG, 256, 0, stream>>>(
                x, Wih0h, (u16*)xgA, tclog2, T_, (s + 1) * Tc);
        if (s < nch)                        // xg for layer-1 chunk s (from h1c)
            gemm_xg<1><<<gemmWG, 256, 0, stream>>>(
                h1c, Wih1h, (u16*)xgB, tclog2, Tc, 0);
    }
}